// Round 9
// baseline (265.824 us; speedup 1.0000x reference)
//
#include <hip/hip_runtime.h>
#include <hip/hip_fp16.h>

#define GAT_H 4
#define GAT_HC 64
#define NEG_SLOPE 0.2f
#define DB 128            // dsts per bin
#define NBMAX 512         // max bins (requires N <= 65536; here N=50000 -> 391)
#define CHUNK 4096        // edges per bin_scatter block
#define EPT 16            // edges per thread in bin_scatter

__device__ __forceinline__ float lrelu(float x) { return x >= 0.f ? x : NEG_SLOPE * x; }

// ---- h = x@W [N,64] (fp16 out); fused per-node attention logits a_src,a_dst [N,4] ----
// Wave-per-row: W column in K VGPRs; x row wave-uniform -> scalar pipe loads.
template <int K, bool CONCAT>
__global__ __launch_bounds__(256) void gemm_attn(
    const float* __restrict__ x, const float* __restrict__ nf,
    const float* __restrict__ gf, const int* __restrict__ batch,
    const float* __restrict__ W,
    const float* __restrict__ att_s, const float* __restrict__ att_d,
    __half* __restrict__ h, float* __restrict__ asrc, float* __restrict__ adst,
    int N, int nwaves)
{
    int lane = threadIdx.x & 63;
    int wid = blockIdx.x * 4 + __builtin_amdgcn_readfirstlane(threadIdx.x >> 6);

    float w[K];
    #pragma unroll
    for (int k = 0; k < K; ++k) w[k] = W[k * 64 + lane];
    float as_c = att_s[lane];
    float ad_c = att_d[lane];

    for (int row = wid; row < N; row += nwaves) {
        float acc = 0.f;
        if (CONCAT) {
            #pragma unroll
            for (int k = 0; k < 9; ++k) acc = fmaf(nf[row * 9 + k], w[k], acc);
            int b = batch[row];
            #pragma unroll
            for (int k = 0; k < 4; ++k) acc = fmaf(gf[b * 4 + k], w[9 + k], acc);
        } else {
            #pragma unroll
            for (int k = 0; k < K; ++k) acc = fmaf(x[(size_t)row * K + k], w[k], acc);
        }
        h[(unsigned)row * 64u + (unsigned)lane] = __float2half(acc);
        float vs = acc * as_c;
        float vd = acc * ad_c;
        #pragma unroll
        for (int off = 8; off; off >>= 1) { vs += __shfl_xor(vs, off); vd += __shfl_xor(vd, off); }
        if ((lane & 15) == 0) {
            asrc[row * GAT_H + (lane >> 4)] = vs;
            adst[row * GAT_H + (lane >> 4)] = vd;
        }
    }
}

// ==================== binned CSR build ====================

// zero bin_cnt + bin_fill without hipMemsetAsync (a small fill costs ~43us in-graph)
__global__ __launch_bounds__(256) void zero_small(unsigned* __restrict__ bin_cnt,
                                                  unsigned* __restrict__ bin_fill)
{
    int t = threadIdx.x;
    bin_cnt[t] = 0; bin_cnt[t + 256] = 0;
    bin_fill[t] = 0; bin_fill[t + 256] = 0;
}

__global__ __launch_bounds__(256) void hist_bins(const int* __restrict__ dst,
                                                 unsigned* __restrict__ bin_cnt, int E)
{
    __shared__ unsigned lh[NBMAX];
    int t = threadIdx.x;
    lh[t] = 0; lh[t + 256] = 0;
    __syncthreads();
    for (int e = blockIdx.x * 256 + t; e < E; e += gridDim.x * 256)
        atomicAdd(&lh[((unsigned)dst[e]) >> 7], 1u);
    __syncthreads();
    unsigned v = lh[t];       if (v) atomicAdd(&bin_cnt[t], v);
    v = lh[t + 256];          if (v) atomicAdd(&bin_cnt[t + 256], v);
}

__global__ __launch_bounds__(256) void scan_bins(const unsigned* __restrict__ bin_cnt,
                                                 unsigned* __restrict__ bin_base,
                                                 int* __restrict__ indptr,
                                                 int nb, int N, int E)
{
    __shared__ unsigned buf[NBMAX];
    int t = threadIdx.x;
    buf[t] = (t < nb) ? bin_cnt[t] : 0u;
    buf[t + 256] = (t + 256 < nb) ? bin_cnt[t + 256] : 0u;
    __syncthreads();
    for (int off = 1; off < NBMAX; off <<= 1) {
        unsigned a = 0, b = 0;
        if (t >= off) a = buf[t - off];
        b = buf[t + 256 - off];
        __syncthreads();
        buf[t] += a; buf[t + 256] += b;
        __syncthreads();
    }
    if (t == 0) { bin_base[0] = 0; indptr[N] = E; }
    if (t < nb) bin_base[t + 1] = buf[t];
    if (t + 256 < nb) bin_base[t + 257] = buf[t + 256];
}

// chunk-local LDS sort by bin, then run-coalesced scatter into bin segments.
// packed edge = (dst<<16)|src  (requires N <= 65536); bin = packed>>23.
__global__ __launch_bounds__(256) void bin_scatter(const int* __restrict__ src,
                                                   const int* __restrict__ dst,
                                                   const unsigned* __restrict__ bin_base,
                                                   unsigned* __restrict__ bin_fill,
                                                   unsigned* __restrict__ binned, int E)
{
    __shared__ unsigned lh[NBMAX];
    __shared__ int goff[NBMAX];
    __shared__ unsigned sorted[CHUNK];
    int t = threadIdx.x;
    lh[t] = 0; lh[t + 256] = 0;
    __syncthreads();
    int e0 = blockIdx.x * CHUNK;

    unsigned pk[EPT]; int bn[EPT]; unsigned rk[EPT];
    #pragma unroll
    for (int i = 0; i < EPT; ++i) {
        int e = e0 + i * 256 + t;
        bn[i] = -1;
        if (e < E) {
            unsigned d = (unsigned)dst[e];
            pk[i] = (d << 16) | (unsigned)src[e];
            bn[i] = (int)(d >> 7);
            rk[i] = atomicAdd(&lh[bn[i]], 1u);
        }
    }
    __syncthreads();
    unsigned c0 = lh[t], c1 = lh[t + 256];   // own-bin counts (pre-scan)
    for (int off = 1; off < NBMAX; off <<= 1) {
        unsigned a = 0, b = 0;
        if (t >= off) a = lh[t - off];
        b = lh[t + 256 - off];
        __syncthreads();
        lh[t] += a; lh[t + 256] += b;
        __syncthreads();
    }
    unsigned x0 = lh[t] - c0, x1 = lh[t + 256] - c1;   // exclusive local bases
    if (c0) { unsigned g = atomicAdd(&bin_fill[t], c0);
              goff[t] = (int)(bin_base[t] + g) - (int)x0; }
    if (c1) { unsigned g = atomicAdd(&bin_fill[t + 256], c1);
              goff[t + 256] = (int)(bin_base[t + 256] + g) - (int)x1; }
    lh[t] = x0; lh[t + 256] = x1;            // own-entry overwrite only
    __syncthreads();
    #pragma unroll
    for (int i = 0; i < EPT; ++i)
        if (bn[i] >= 0) sorted[lh[bn[i]] + rk[i]] = pk[i];
    __syncthreads();
    int T = min(CHUNK, E - e0);
    for (int j = t; j < T; j += 256) {
        unsigned p = sorted[j];
        binned[goff[p >> 23] + j] = p;       // piecewise-contiguous runs
    }
}

// block per bin; LDS counting-sort by dst_local -> final dst-sorted csr_src + indptr
__global__ __launch_bounds__(256) void bin_finalize(const unsigned* __restrict__ binned,
                                                    const unsigned* __restrict__ bin_base,
                                                    int* __restrict__ csr_src,
                                                    int* __restrict__ indptr, int N)
{
    __shared__ unsigned lh[DB];
    __shared__ unsigned fill[DB];
    int t = threadIdx.x, b = blockIdx.x;
    unsigned base = bin_base[b];
    unsigned cnt = bin_base[b + 1] - base;
    if (t < DB) lh[t] = 0;
    __syncthreads();
    for (unsigned i = t; i < cnt; i += 256)
        atomicAdd(&lh[(binned[base + i] >> 16) & (DB - 1)], 1u);
    __syncthreads();
    unsigned c0 = (t < DB) ? lh[t] : 0;
    for (int off = 1; off < DB; off <<= 1) {
        unsigned a = 0;
        if (t >= off && t < DB) a = lh[t - off];
        __syncthreads();
        if (t < DB) lh[t] += a;
        __syncthreads();
    }
    if (t < DB) {
        unsigned excl = lh[t] - c0;
        int d = b * DB + t;
        if (d < N) indptr[d] = (int)(base + excl);
        fill[t] = excl;
    }
    __syncthreads();
    for (unsigned i = t; i < cnt; i += 256) {
        unsigned p = binned[base + i];
        unsigned pos = atomicAdd(&fill[(p >> 16) & (DB - 1)], 1u);
        csr_src[base + pos] = (int)(p & 0xFFFFu);
    }
}

// ==================== aggregation ====================
// Wave per node (persistent). s[i] forced uniform (readfirstlane) -> csr + asrc
// go through the scalar pipe (asrc as uniform float4 + per-lane cndmask select);
// the only per-edge VMEM gather is the 128-B fp16 h row.
template <bool RELU>
__global__ __launch_bounds__(256) void aggregate(
    const __half* __restrict__ h, const float* __restrict__ asrc,
    const float* __restrict__ adst, const int* __restrict__ indptr,
    const int* __restrict__ csr_src, const float* __restrict__ bias,
    float* __restrict__ xout, int N, int nwaves)
{
    int lane = threadIdx.x & 63;
    int wid = blockIdx.x * 4 + __builtin_amdgcn_readfirstlane(threadIdx.x >> 6);
    unsigned h16 = (unsigned)(lane >> 4);   // head
    float bias_c = bias[lane];

    for (int node = wid; node < N; node += nwaves) {
        int beg = __builtin_amdgcn_readfirstlane(indptr[node]);
        int end = __builtin_amdgcn_readfirstlane(indptr[node + 1]);
        unsigned un = (unsigned)node;

        float adst_n = adst[un * 4u + h16];
        float p0 = __expf(lrelu(asrc[un * 4u + h16] + adst_n));   // self loop
        float sacc = p0;
        float acc = __half2float(h[un * 64u + (unsigned)lane]) * p0;

        int e = beg;
        for (; e + 8 <= end; e += 8) {
            int s[8]; float a[8], hv[8];
            #pragma unroll
            for (int i = 0; i < 8; ++i) s[i] = __builtin_amdgcn_readfirstlane(csr_src[e + i]);
            #pragma unroll
            for (int i = 0; i < 8; ++i) {
                float4 av = *reinterpret_cast<const float4*>(asrc + (unsigned)s[i] * 4u);
                a[i] = (h16 < 2u) ? (h16 == 0u ? av.x : av.y)
                                  : (h16 == 2u ? av.z : av.w);
            }
            #pragma unroll
            for (int i = 0; i < 8; ++i)
                hv[i] = __half2float(h[(unsigned)s[i] * 64u + (unsigned)lane]);
            #pragma unroll
            for (int i = 0; i < 8; ++i) {
                float p = __expf(lrelu(a[i] + adst_n));
                sacc += p;
                acc = fmaf(hv[i], p, acc);
            }
        }
        for (; e + 2 <= end; e += 2) {
            int s0 = __builtin_amdgcn_readfirstlane(csr_src[e]);
            int s1 = __builtin_amdgcn_readfirstlane(csr_src[e + 1]);
            float4 av0 = *reinterpret_cast<const float4*>(asrc + (unsigned)s0 * 4u);
            float4 av1 = *reinterpret_cast<const float4*>(asrc + (unsigned)s1 * 4u);
            float a0 = (h16 < 2u) ? (h16 == 0u ? av0.x : av0.y)
                                  : (h16 == 2u ? av0.z : av0.w);
            float a1 = (h16 < 2u) ? (h16 == 0u ? av1.x : av1.y)
                                  : (h16 == 2u ? av1.z : av1.w);
            float h0 = __half2float(h[(unsigned)s0 * 64u + (unsigned)lane]);
            float h1 = __half2float(h[(unsigned)s1 * 64u + (unsigned)lane]);
            float pa = __expf(lrelu(a0 + adst_n));
            float pb = __expf(lrelu(a1 + adst_n));
            sacc += pa + pb;
            acc = fmaf(h0, pa, acc);
            acc = fmaf(h1, pb, acc);
        }
        if (e < end) {
            int s = __builtin_amdgcn_readfirstlane(csr_src[e]);
            float4 av = *reinterpret_cast<const float4*>(asrc + (unsigned)s * 4u);
            float a = (h16 < 2u) ? (h16 == 0u ? av.x : av.y)
                                 : (h16 == 2u ? av.z : av.w);
            float p = __expf(lrelu(a + adst_n));
            sacc += p;
            acc = fmaf(__half2float(h[(unsigned)s * 64u + (unsigned)lane]), p, acc);
        }

        float o = acc / sacc + bias_c;
        if (RELU) o = fmaxf(o, 0.f);
        xout[un * 64u + (unsigned)lane] = o;
    }
}

// ---- fused scatter-mean pooling (batch_idx sorted -> binary search) + MLP head ----
__global__ void pool_mlp(const float* __restrict__ x, const int* __restrict__ batch, int N,
                         const float* __restrict__ W0, const float* __restrict__ b0,
                         const float* __restrict__ W1, const float* __restrict__ b1,
                         const float* __restrict__ W2, const float* __restrict__ b2,
                         const float* __restrict__ W3, const float* __restrict__ b3,
                         float* __restrict__ out)
{
    __shared__ int bounds[2];
    __shared__ float red[4][64];
    __shared__ float hb[64];
    int b = blockIdx.x, t = threadIdx.x;

    if (t < 2) {
        int target = b + t;
        int lo = 0, hi = N;
        while (lo < hi) {
            int mid = (lo + hi) >> 1;
            if (batch[mid] < target) lo = mid + 1; else hi = mid;
        }
        bounds[t] = lo;
    }
    __syncthreads();
    int beg = bounds[0], end = bounds[1];

    int c = t & 63, w = t >> 6;
    float sum = 0.f;
    for (int n = beg + w; n < end; n += 4) sum += x[(size_t)n * 64 + c];
    red[w][c] = sum;
    __syncthreads();
    if (t < 64) {
        float v = red[0][t] + red[1][t] + red[2][t] + red[3][t];
        float cb = fmaxf((float)(end - beg), 1.0f);
        hb[t] = v / cb;
    }
    __syncthreads();

    float v0 = 0.f;
    if (t < 64) {
        v0 = b0[t];
        for (int k = 0; k < 64; ++k) v0 = fmaf(hb[k], W0[k * 64 + t], v0);
        v0 = fmaxf(v0, 0.f);
    }
    __syncthreads(); if (t < 64) hb[t] = v0; __syncthreads();
    if (t < 64) {
        v0 = b1[t];
        for (int k = 0; k < 64; ++k) v0 = fmaf(hb[k], W1[k * 64 + t], v0);
        v0 = fmaxf(v0, 0.f);
    }
    __syncthreads(); if (t < 64) hb[t] = v0; __syncthreads();
    if (t < 64) {
        v0 = b2[t];
        for (int k = 0; k < 64; ++k) v0 = fmaf(hb[k], W2[k * 64 + t], v0);
        v0 = fmaxf(v0, 0.f);
    }
    __syncthreads(); if (t < 64) hb[t] = v0; __syncthreads();
    if (t < 64) {
        float r = hb[t] * W3[t];
        #pragma unroll
        for (int off = 32; off; off >>= 1) r += __shfl_xor(r, off);
        if (t == 0) out[b] = r + b3[0];
    }
}

extern "C" void kernel_launch(void* const* d_in, const int* in_sizes, int n_in,
                              void* d_out, int out_size, void* d_ws, size_t ws_size,
                              hipStream_t stream)
{
    const float* node_feats = (const float*)d_in[0];
    const float* glob       = (const float*)d_in[1];
    const int*   edge_index = (const int*)d_in[2];
    const int*   batch      = (const int*)d_in[3];
    const float* W[3]  = {(const float*)d_in[4],  (const float*)d_in[8],  (const float*)d_in[12]};
    const float* As[3] = {(const float*)d_in[5],  (const float*)d_in[9],  (const float*)d_in[13]};
    const float* Ad[3] = {(const float*)d_in[6],  (const float*)d_in[10], (const float*)d_in[14]};
    const float* Bi[3] = {(const float*)d_in[7],  (const float*)d_in[11], (const float*)d_in[15]};
    const float* mW0 = (const float*)d_in[16]; const float* mb0 = (const float*)d_in[17];
    const float* mW1 = (const float*)d_in[18]; const float* mb1 = (const float*)d_in[19];
    const float* mW2 = (const float*)d_in[20]; const float* mb2 = (const float*)d_in[21];
    const float* mW3 = (const float*)d_in[22]; const float* mb3 = (const float*)d_in[23];
    float* out = (float*)d_out;

    int N = in_sizes[0] / 9;
    int E = in_sizes[2] / 2;
    int B = in_sizes[1] / 4;
    const int* esrc = edge_index;
    const int* edst = edge_index + E;
    int nb = (N + DB - 1) / DB;

    // workspace layout
    char* ws = (char*)d_ws;
    size_t off = 0;
    auto alloc = [&](size_t bytes) -> void* {
        void* p = ws + off;
        off = (off + bytes + 255) & ~(size_t)255;
        return p;
    };
    __half*   hbuf     = (__half*)alloc((size_t)N * 64 * 2);
    float*    xbuf     = (float*)alloc((size_t)N * 64 * 4);
    float*    asrc     = (float*)alloc((size_t)N * GAT_H * 4);
    float*    adst     = (float*)alloc((size_t)N * GAT_H * 4);
    int*      indptr   = (int*)alloc((size_t)(N + 1) * 4);
    int*      csr_src  = (int*)alloc((size_t)E * 4);
    unsigned* binned   = (unsigned*)alloc((size_t)E * 4);
    unsigned* bin_cnt  = (unsigned*)alloc(NBMAX * 4);
    unsigned* bin_base = (unsigned*)alloc((NBMAX + 1) * 4);
    unsigned* bin_fill = (unsigned*)alloc(NBMAX * 4);
    (void)ws_size;

    // CSR build (binned counting sort; once — shared by all 3 layers)
    zero_small<<<1, 256, 0, stream>>>(bin_cnt, bin_fill);
    hist_bins<<<400, 256, 0, stream>>>(edst, bin_cnt, E);
    scan_bins<<<1, 256, 0, stream>>>(bin_cnt, bin_base, indptr, nb, N, E);
    bin_scatter<<<(E + CHUNK - 1) / CHUNK, 256, 0, stream>>>(esrc, edst, bin_base, bin_fill,
                                                             binned, E);
    bin_finalize<<<nb, 256, 0, stream>>>(binned, bin_base, csr_src, indptr, N);

    const int gemmBlocks = 1024;
    const int aggBlocks = 6250;     // 25000 waves, ~2 nodes/wave
    // layer 0 (K=13, concat fused)
    gemm_attn<13, true><<<gemmBlocks, 256, 0, stream>>>(nullptr, node_feats, glob, batch,
                                                        W[0], As[0], Ad[0], hbuf, asrc, adst,
                                                        N, gemmBlocks * 4);
    aggregate<true><<<aggBlocks, 256, 0, stream>>>(hbuf, asrc, adst, indptr, csr_src, Bi[0],
                                                   xbuf, N, aggBlocks * 4);
    // layer 1 (K=64)
    gemm_attn<64, false><<<gemmBlocks, 256, 0, stream>>>(xbuf, nullptr, nullptr, nullptr,
                                                         W[1], As[1], Ad[1], hbuf, asrc, adst,
                                                         N, gemmBlocks * 4);
    aggregate<true><<<aggBlocks, 256, 0, stream>>>(hbuf, asrc, adst, indptr, csr_src, Bi[1],
                                                   xbuf, N, aggBlocks * 4);
    // layer 2 (K=64, no act)
    gemm_attn<64, false><<<gemmBlocks, 256, 0, stream>>>(xbuf, nullptr, nullptr, nullptr,
                                                         W[2], As[2], Ad[2], hbuf, asrc, adst,
                                                         N, gemmBlocks * 4);
    aggregate<false><<<aggBlocks, 256, 0, stream>>>(hbuf, asrc, adst, indptr, csr_src, Bi[2],
                                                    xbuf, N, aggBlocks * 4);

    // fused pooling + MLP head
    pool_mlp<<<B, 256, 0, stream>>>(xbuf, batch, N,
                                    mW0, mb0, mW1, mb1, mW2, mb2, mW3, mb3, out);
}

// Round 10
// 188.439 us; speedup vs baseline: 1.4107x; 1.4107x over previous
//
#include <hip/hip_runtime.h>
#include <hip/hip_fp16.h>

#define GAT_H 4
#define GAT_HC 64
#define NEG_SLOPE 0.2f
#define DB 128            // dsts per bin
#define NBMAX 512         // max bins (requires N <= 65536; here N=50000 -> 391)
#define CHUNK 4096        // edges per bin_scatter block
#define EPT 16            // edges per thread in bin_scatter

__device__ __forceinline__ float lrelu(float x) { return x >= 0.f ? x : NEG_SLOPE * x; }

// ---- h = x@W [N,64] (fp16 out); fused per-node attention logits a_src,a_dst [N,4] ----
// Wave-per-row: W column in K VGPRs; x row wave-uniform -> scalar pipe loads.
template <int K, bool CONCAT>
__global__ __launch_bounds__(256) void gemm_attn(
    const float* __restrict__ x, const float* __restrict__ nf,
    const float* __restrict__ gf, const int* __restrict__ batch,
    const float* __restrict__ W,
    const float* __restrict__ att_s, const float* __restrict__ att_d,
    __half* __restrict__ h, float* __restrict__ asrc, float* __restrict__ adst,
    int N, int nwaves)
{
    int lane = threadIdx.x & 63;
    int wid = blockIdx.x * 4 + __builtin_amdgcn_readfirstlane(threadIdx.x >> 6);

    float w[K];
    #pragma unroll
    for (int k = 0; k < K; ++k) w[k] = W[k * 64 + lane];
    float as_c = att_s[lane];
    float ad_c = att_d[lane];

    for (int row = wid; row < N; row += nwaves) {
        float acc = 0.f;
        if (CONCAT) {
            #pragma unroll
            for (int k = 0; k < 9; ++k) acc = fmaf(nf[row * 9 + k], w[k], acc);
            int b = batch[row];
            #pragma unroll
            for (int k = 0; k < 4; ++k) acc = fmaf(gf[b * 4 + k], w[9 + k], acc);
        } else {
            #pragma unroll
            for (int k = 0; k < K; ++k) acc = fmaf(x[(size_t)row * K + k], w[k], acc);
        }
        h[(unsigned)row * 64u + (unsigned)lane] = __float2half(acc);
        float vs = acc * as_c;
        float vd = acc * ad_c;
        #pragma unroll
        for (int off = 8; off; off >>= 1) { vs += __shfl_xor(vs, off); vd += __shfl_xor(vd, off); }
        if ((lane & 15) == 0) {
            asrc[row * GAT_H + (lane >> 4)] = vs;
            adst[row * GAT_H + (lane >> 4)] = vd;
        }
    }
}

// ==================== binned CSR build ====================

// zero bin_cnt + bin_fill without hipMemsetAsync (a small fill costs ~43us in-graph)
__global__ __launch_bounds__(256) void zero_small(unsigned* __restrict__ bin_cnt,
                                                  unsigned* __restrict__ bin_fill)
{
    int t = threadIdx.x;
    bin_cnt[t] = 0; bin_cnt[t + 256] = 0;
    bin_fill[t] = 0; bin_fill[t + 256] = 0;
}

__global__ __launch_bounds__(256) void hist_bins(const int* __restrict__ dst,
                                                 unsigned* __restrict__ bin_cnt, int E)
{
    __shared__ unsigned lh[NBMAX];
    int t = threadIdx.x;
    lh[t] = 0; lh[t + 256] = 0;
    __syncthreads();
    for (int e = blockIdx.x * 256 + t; e < E; e += gridDim.x * 256)
        atomicAdd(&lh[((unsigned)dst[e]) >> 7], 1u);
    __syncthreads();
    unsigned v = lh[t];       if (v) atomicAdd(&bin_cnt[t], v);
    v = lh[t + 256];          if (v) atomicAdd(&bin_cnt[t + 256], v);
}

__global__ __launch_bounds__(256) void scan_bins(const unsigned* __restrict__ bin_cnt,
                                                 unsigned* __restrict__ bin_base,
                                                 int* __restrict__ indptr,
                                                 int nb, int N, int E)
{
    __shared__ unsigned buf[NBMAX];
    int t = threadIdx.x;
    buf[t] = (t < nb) ? bin_cnt[t] : 0u;
    buf[t + 256] = (t + 256 < nb) ? bin_cnt[t + 256] : 0u;
    __syncthreads();
    for (int off = 1; off < NBMAX; off <<= 1) {
        unsigned a = 0, b = 0;
        if (t >= off) a = buf[t - off];
        b = buf[t + 256 - off];
        __syncthreads();
        buf[t] += a; buf[t + 256] += b;
        __syncthreads();
    }
    if (t == 0) { bin_base[0] = 0; indptr[N] = E; }
    if (t < nb) bin_base[t + 1] = buf[t];
    if (t + 256 < nb) bin_base[t + 257] = buf[t + 256];
}

// chunk-local LDS sort by bin, then run-coalesced scatter into bin segments.
// packed edge = (dst<<16)|src  (requires N <= 65536); bin = packed>>23.
__global__ __launch_bounds__(256) void bin_scatter(const int* __restrict__ src,
                                                   const int* __restrict__ dst,
                                                   const unsigned* __restrict__ bin_base,
                                                   unsigned* __restrict__ bin_fill,
                                                   unsigned* __restrict__ binned, int E)
{
    __shared__ unsigned lh[NBMAX];
    __shared__ int goff[NBMAX];
    __shared__ unsigned sorted[CHUNK];
    int t = threadIdx.x;
    lh[t] = 0; lh[t + 256] = 0;
    __syncthreads();
    int e0 = blockIdx.x * CHUNK;

    unsigned pk[EPT]; int bn[EPT]; unsigned rk[EPT];
    #pragma unroll
    for (int i = 0; i < EPT; ++i) {
        int e = e0 + i * 256 + t;
        bn[i] = -1;
        if (e < E) {
            unsigned d = (unsigned)dst[e];
            pk[i] = (d << 16) | (unsigned)src[e];
            bn[i] = (int)(d >> 7);
            rk[i] = atomicAdd(&lh[bn[i]], 1u);
        }
    }
    __syncthreads();
    unsigned c0 = lh[t], c1 = lh[t + 256];   // own-bin counts (pre-scan)
    for (int off = 1; off < NBMAX; off <<= 1) {
        unsigned a = 0, b = 0;
        if (t >= off) a = lh[t - off];
        b = lh[t + 256 - off];
        __syncthreads();
        lh[t] += a; lh[t + 256] += b;
        __syncthreads();
    }
    unsigned x0 = lh[t] - c0, x1 = lh[t + 256] - c1;   // exclusive local bases
    if (c0) { unsigned g = atomicAdd(&bin_fill[t], c0);
              goff[t] = (int)(bin_base[t] + g) - (int)x0; }
    if (c1) { unsigned g = atomicAdd(&bin_fill[t + 256], c1);
              goff[t + 256] = (int)(bin_base[t + 256] + g) - (int)x1; }
    lh[t] = x0; lh[t + 256] = x1;            // own-entry overwrite only
    __syncthreads();
    #pragma unroll
    for (int i = 0; i < EPT; ++i)
        if (bn[i] >= 0) sorted[lh[bn[i]] + rk[i]] = pk[i];
    __syncthreads();
    int T = min(CHUNK, E - e0);
    for (int j = t; j < T; j += 256) {
        unsigned p = sorted[j];
        binned[goff[p >> 23] + j] = p;       // piecewise-contiguous runs
    }
}

// block per bin; LDS counting-sort by dst_local -> final dst-sorted csr_src + indptr
__global__ __launch_bounds__(256) void bin_finalize(const unsigned* __restrict__ binned,
                                                    const unsigned* __restrict__ bin_base,
                                                    int* __restrict__ csr_src,
                                                    int* __restrict__ indptr, int N)
{
    __shared__ unsigned lh[DB];
    __shared__ unsigned fill[DB];
    int t = threadIdx.x, b = blockIdx.x;
    unsigned base = bin_base[b];
    unsigned cnt = bin_base[b + 1] - base;
    if (t < DB) lh[t] = 0;
    __syncthreads();
    for (unsigned i = t; i < cnt; i += 256)
        atomicAdd(&lh[(binned[base + i] >> 16) & (DB - 1)], 1u);
    __syncthreads();
    unsigned c0 = (t < DB) ? lh[t] : 0;
    for (int off = 1; off < DB; off <<= 1) {
        unsigned a = 0;
        if (t >= off && t < DB) a = lh[t - off];
        __syncthreads();
        if (t < DB) lh[t] += a;
        __syncthreads();
    }
    if (t < DB) {
        unsigned excl = lh[t] - c0;
        int d = b * DB + t;
        if (d < N) indptr[d] = (int)(base + excl);
        fill[t] = excl;
    }
    __syncthreads();
    for (unsigned i = t; i < cnt; i += 256) {
        unsigned p = binned[base + i];
        unsigned pos = atomicAdd(&fill[(p >> 16) & (DB - 1)], 1u);
        csr_src[base + pos] = (int)(p & 0xFFFFu);
    }
}

// ==================== aggregation ====================
// Wave per node (persistent). beg/end in SGPR -> csr_src reads are scalar loads;
// 8-deep independent VMEM gather chains (asrc dword + fp16 h row = 128B/edge).
template <bool RELU>
__global__ __launch_bounds__(256) void aggregate(
    const __half* __restrict__ h, const float* __restrict__ asrc,
    const float* __restrict__ adst, const int* __restrict__ indptr,
    const int* __restrict__ csr_src, const float* __restrict__ bias,
    float* __restrict__ xout, int N, int nwaves)
{
    int lane = threadIdx.x & 63;
    int wid = blockIdx.x * 4 + __builtin_amdgcn_readfirstlane(threadIdx.x >> 6);
    unsigned h16 = (unsigned)(lane >> 4);   // head
    float bias_c = bias[lane];

    for (int node = wid; node < N; node += nwaves) {
        int beg = __builtin_amdgcn_readfirstlane(indptr[node]);
        int end = __builtin_amdgcn_readfirstlane(indptr[node + 1]);
        unsigned un = (unsigned)node;

        float adst_n = adst[un * 4u + h16];
        float p0 = __expf(lrelu(asrc[un * 4u + h16] + adst_n));   // self loop
        float sacc = p0;
        float acc = __half2float(h[un * 64u + (unsigned)lane]) * p0;

        int e = beg;
        for (; e + 8 <= end; e += 8) {
            int s[8]; float a[8], hv[8];
            #pragma unroll
            for (int i = 0; i < 8; ++i) s[i] = csr_src[e + i];           // scalar loads
            #pragma unroll
            for (int i = 0; i < 8; ++i) a[i] = asrc[(unsigned)s[i] * 4u + h16];
            #pragma unroll
            for (int i = 0; i < 8; ++i)
                hv[i] = __half2float(h[(unsigned)s[i] * 64u + (unsigned)lane]);
            #pragma unroll
            for (int i = 0; i < 8; ++i) {
                float p = __expf(lrelu(a[i] + adst_n));
                sacc += p;
                acc = fmaf(hv[i], p, acc);
            }
        }
        for (; e + 2 <= end; e += 2) {
            int s0 = csr_src[e], s1 = csr_src[e + 1];
            float a0 = asrc[(unsigned)s0 * 4u + h16];
            float a1 = asrc[(unsigned)s1 * 4u + h16];
            float h0 = __half2float(h[(unsigned)s0 * 64u + (unsigned)lane]);
            float h1 = __half2float(h[(unsigned)s1 * 64u + (unsigned)lane]);
            float pa = __expf(lrelu(a0 + adst_n));
            float pb = __expf(lrelu(a1 + adst_n));
            sacc += pa + pb;
            acc = fmaf(h0, pa, acc);
            acc = fmaf(h1, pb, acc);
        }
        if (e < end) {
            int s = csr_src[e];
            float p = __expf(lrelu(asrc[(unsigned)s * 4u + h16] + adst_n));
            sacc += p;
            acc = fmaf(__half2float(h[(unsigned)s * 64u + (unsigned)lane]), p, acc);
        }

        float o = acc / sacc + bias_c;
        if (RELU) o = fmaxf(o, 0.f);
        xout[un * 64u + (unsigned)lane] = o;
    }
}

// ---- fused scatter-mean pooling (batch_idx sorted -> binary search) + MLP head ----
__global__ void pool_mlp(const float* __restrict__ x, const int* __restrict__ batch, int N,
                         const float* __restrict__ W0, const float* __restrict__ b0,
                         const float* __restrict__ W1, const float* __restrict__ b1,
                         const float* __restrict__ W2, const float* __restrict__ b2,
                         const float* __restrict__ W3, const float* __restrict__ b3,
                         float* __restrict__ out)
{
    __shared__ int bounds[2];
    __shared__ float red[4][64];
    __shared__ float hb[64];
    int b = blockIdx.x, t = threadIdx.x;

    if (t < 2) {
        int target = b + t;
        int lo = 0, hi = N;
        while (lo < hi) {
            int mid = (lo + hi) >> 1;
            if (batch[mid] < target) lo = mid + 1; else hi = mid;
        }
        bounds[t] = lo;
    }
    __syncthreads();
    int beg = bounds[0], end = bounds[1];

    int c = t & 63, w = t >> 6;
    float sum = 0.f;
    for (int n = beg + w; n < end; n += 4) sum += x[(size_t)n * 64 + c];
    red[w][c] = sum;
    __syncthreads();
    if (t < 64) {
        float v = red[0][t] + red[1][t] + red[2][t] + red[3][t];
        float cb = fmaxf((float)(end - beg), 1.0f);
        hb[t] = v / cb;
    }
    __syncthreads();

    float v0 = 0.f;
    if (t < 64) {
        v0 = b0[t];
        for (int k = 0; k < 64; ++k) v0 = fmaf(hb[k], W0[k * 64 + t], v0);
        v0 = fmaxf(v0, 0.f);
    }
    __syncthreads(); if (t < 64) hb[t] = v0; __syncthreads();
    if (t < 64) {
        v0 = b1[t];
        for (int k = 0; k < 64; ++k) v0 = fmaf(hb[k], W1[k * 64 + t], v0);
        v0 = fmaxf(v0, 0.f);
    }
    __syncthreads(); if (t < 64) hb[t] = v0; __syncthreads();
    if (t < 64) {
        v0 = b2[t];
        for (int k = 0; k < 64; ++k) v0 = fmaf(hb[k], W2[k * 64 + t], v0);
        v0 = fmaxf(v0, 0.f);
    }
    __syncthreads(); if (t < 64) hb[t] = v0; __syncthreads();
    if (t < 64) {
        float r = hb[t] * W3[t];
        #pragma unroll
        for (int off = 32; off; off >>= 1) r += __shfl_xor(r, off);
        if (t == 0) out[b] = r + b3[0];
    }
}

extern "C" void kernel_launch(void* const* d_in, const int* in_sizes, int n_in,
                              void* d_out, int out_size, void* d_ws, size_t ws_size,
                              hipStream_t stream)
{
    const float* node_feats = (const float*)d_in[0];
    const float* glob       = (const float*)d_in[1];
    const int*   edge_index = (const int*)d_in[2];
    const int*   batch      = (const int*)d_in[3];
    const float* W[3]  = {(const float*)d_in[4],  (const float*)d_in[8],  (const float*)d_in[12]};
    const float* As[3] = {(const float*)d_in[5],  (const float*)d_in[9],  (const float*)d_in[13]};
    const float* Ad[3] = {(const float*)d_in[6],  (const float*)d_in[10], (const float*)d_in[14]};
    const float* Bi[3] = {(const float*)d_in[7],  (const float*)d_in[11], (const float*)d_in[15]};
    const float* mW0 = (const float*)d_in[16]; const float* mb0 = (const float*)d_in[17];
    const float* mW1 = (const float*)d_in[18]; const float* mb1 = (const float*)d_in[19];
    const float* mW2 = (const float*)d_in[20]; const float* mb2 = (const float*)d_in[21];
    const float* mW3 = (const float*)d_in[22]; const float* mb3 = (const float*)d_in[23];
    float* out = (float*)d_out;

    int N = in_sizes[0] / 9;
    int E = in_sizes[2] / 2;
    int B = in_sizes[1] / 4;
    const int* esrc = edge_index;
    const int* edst = edge_index + E;
    int nb = (N + DB - 1) / DB;

    // workspace layout
    char* ws = (char*)d_ws;
    size_t off = 0;
    auto alloc = [&](size_t bytes) -> void* {
        void* p = ws + off;
        off = (off + bytes + 255) & ~(size_t)255;
        return p;
    };
    __half*   hbuf     = (__half*)alloc((size_t)N * 64 * 2);
    float*    xbuf     = (float*)alloc((size_t)N * 64 * 4);
    float*    asrc     = (float*)alloc((size_t)N * GAT_H * 4);
    float*    adst     = (float*)alloc((size_t)N * GAT_H * 4);
    int*      indptr   = (int*)alloc((size_t)(N + 1) * 4);
    int*      csr_src  = (int*)alloc((size_t)E * 4);
    unsigned* binned   = (unsigned*)alloc((size_t)E * 4);
    unsigned* bin_cnt  = (unsigned*)alloc(NBMAX * 4);
    unsigned* bin_base = (unsigned*)alloc((NBMAX + 1) * 4);
    unsigned* bin_fill = (unsigned*)alloc(NBMAX * 4);
    (void)ws_size;

    // CSR build (binned counting sort; once — shared by all 3 layers)
    zero_small<<<1, 256, 0, stream>>>(bin_cnt, bin_fill);
    hist_bins<<<400, 256, 0, stream>>>(edst, bin_cnt, E);
    scan_bins<<<1, 256, 0, stream>>>(bin_cnt, bin_base, indptr, nb, N, E);
    bin_scatter<<<(E + CHUNK - 1) / CHUNK, 256, 0, stream>>>(esrc, edst, bin_base, bin_fill,
                                                             binned, E);
    bin_finalize<<<nb, 256, 0, stream>>>(binned, bin_base, csr_src, indptr, N);

    const int gemmBlocks = 1024;
    const int aggBlocks = 6250;     // 25000 waves, ~2 nodes/wave
    // layer 0 (K=13, concat fused)
    gemm_attn<13, true><<<gemmBlocks, 256, 0, stream>>>(nullptr, node_feats, glob, batch,
                                                        W[0], As[0], Ad[0], hbuf, asrc, adst,
                                                        N, gemmBlocks * 4);
    aggregate<true><<<aggBlocks, 256, 0, stream>>>(hbuf, asrc, adst, indptr, csr_src, Bi[0],
                                                   xbuf, N, aggBlocks * 4);
    // layer 1 (K=64)
    gemm_attn<64, false><<<gemmBlocks, 256, 0, stream>>>(xbuf, nullptr, nullptr, nullptr,
                                                         W[1], As[1], Ad[1], hbuf, asrc, adst,
                                                         N, gemmBlocks * 4);
    aggregate<true><<<aggBlocks, 256, 0, stream>>>(hbuf, asrc, adst, indptr, csr_src, Bi[1],
                                                   xbuf, N, aggBlocks * 4);
    // layer 2 (K=64, no act)
    gemm_attn<64, false><<<gemmBlocks, 256, 0, stream>>>(xbuf, nullptr, nullptr, nullptr,
                                                         W[2], As[2], Ad[2], hbuf, asrc, adst,
                                                         N, gemmBlocks * 4);
    aggregate<false><<<aggBlocks, 256, 0, stream>>>(hbuf, asrc, adst, indptr, csr_src, Bi[2],
                                                    xbuf, N, aggBlocks * 4);

    // fused pooling + MLP head
    pool_mlp<<<B, 256, 0, stream>>>(xbuf, batch, N,
                                    mW0, mb0, mW1, mb1, mW2, mb2, mW3, mb3, out);
}

// Round 11
// 184.299 us; speedup vs baseline: 1.4424x; 1.0225x over previous
//
#include <hip/hip_runtime.h>
#include <hip/hip_fp16.h>

#define GAT_H 4
#define GAT_HC 64
#define NEG_SLOPE 0.2f
#define DB 128            // dsts per bin
#define NBMAX 512         // max bins (requires N <= 65536; here N=50000 -> 391)
#define CHUNK 4096        // edges per bin_scatter block
#define EPT 16            // edges per thread in bin_scatter

__device__ __forceinline__ float lrelu(float x) { return x >= 0.f ? x : NEG_SLOPE * x; }

// ---- h = x@W [N,64] (fp16 out); fused per-node attention logits a_src,a_dst [N,4] ----
// Wave-per-row: W column in K VGPRs; x row wave-uniform -> scalar pipe loads.
template <int K, bool CONCAT>
__global__ __launch_bounds__(256) void gemm_attn(
    const float* __restrict__ x, const float* __restrict__ nf,
    const float* __restrict__ gf, const int* __restrict__ batch,
    const float* __restrict__ W,
    const float* __restrict__ att_s, const float* __restrict__ att_d,
    __half* __restrict__ h, float* __restrict__ asrc, float* __restrict__ adst,
    int N, int nwaves)
{
    int lane = threadIdx.x & 63;
    int wid = blockIdx.x * 4 + __builtin_amdgcn_readfirstlane(threadIdx.x >> 6);

    float w[K];
    #pragma unroll
    for (int k = 0; k < K; ++k) w[k] = W[k * 64 + lane];
    float as_c = att_s[lane];
    float ad_c = att_d[lane];

    for (int row = wid; row < N; row += nwaves) {
        float acc = 0.f;
        if (CONCAT) {
            #pragma unroll
            for (int k = 0; k < 9; ++k) acc = fmaf(nf[row * 9 + k], w[k], acc);
            int b = batch[row];
            #pragma unroll
            for (int k = 0; k < 4; ++k) acc = fmaf(gf[b * 4 + k], w[9 + k], acc);
        } else {
            #pragma unroll
            for (int k = 0; k < K; ++k) acc = fmaf(x[(size_t)row * K + k], w[k], acc);
        }
        h[(unsigned)row * 64u + (unsigned)lane] = __float2half(acc);
        float vs = acc * as_c;
        float vd = acc * ad_c;
        #pragma unroll
        for (int off = 8; off; off >>= 1) { vs += __shfl_xor(vs, off); vd += __shfl_xor(vd, off); }
        if ((lane & 15) == 0) {
            asrc[row * GAT_H + (lane >> 4)] = vs;
            adst[row * GAT_H + (lane >> 4)] = vd;
        }
    }
}

// ==================== binned CSR build ====================

// zero bin_cnt + bin_fill without hipMemsetAsync (a small fill costs ~43us in-graph)
__global__ __launch_bounds__(256) void zero_small(unsigned* __restrict__ bin_cnt,
                                                  unsigned* __restrict__ bin_fill)
{
    int t = threadIdx.x;
    bin_cnt[t] = 0; bin_cnt[t + 256] = 0;
    bin_fill[t] = 0; bin_fill[t + 256] = 0;
}

__global__ __launch_bounds__(256) void hist_bins(const int* __restrict__ dst,
                                                 unsigned* __restrict__ bin_cnt, int E)
{
    __shared__ unsigned lh[NBMAX];
    int t = threadIdx.x;
    lh[t] = 0; lh[t + 256] = 0;
    __syncthreads();
    for (int e = blockIdx.x * 256 + t; e < E; e += gridDim.x * 256)
        atomicAdd(&lh[((unsigned)dst[e]) >> 7], 1u);
    __syncthreads();
    unsigned v = lh[t];       if (v) atomicAdd(&bin_cnt[t], v);
    v = lh[t + 256];          if (v) atomicAdd(&bin_cnt[t + 256], v);
}

__global__ __launch_bounds__(256) void scan_bins(const unsigned* __restrict__ bin_cnt,
                                                 unsigned* __restrict__ bin_base,
                                                 int* __restrict__ indptr,
                                                 int nb, int N, int E)
{
    __shared__ unsigned buf[NBMAX];
    int t = threadIdx.x;
    buf[t] = (t < nb) ? bin_cnt[t] : 0u;
    buf[t + 256] = (t + 256 < nb) ? bin_cnt[t + 256] : 0u;
    __syncthreads();
    for (int off = 1; off < NBMAX; off <<= 1) {
        unsigned a = 0, b = 0;
        if (t >= off) a = buf[t - off];
        b = buf[t + 256 - off];
        __syncthreads();
        buf[t] += a; buf[t + 256] += b;
        __syncthreads();
    }
    if (t == 0) { bin_base[0] = 0; indptr[N] = E; }
    if (t < nb) bin_base[t + 1] = buf[t];
    if (t + 256 < nb) bin_base[t + 257] = buf[t + 256];
}

// chunk-local LDS sort by bin, then run-coalesced scatter into bin segments.
// packed edge = (dst<<16)|src  (requires N <= 65536); bin = packed>>23.
__global__ __launch_bounds__(256) void bin_scatter(const int* __restrict__ src,
                                                   const int* __restrict__ dst,
                                                   const unsigned* __restrict__ bin_base,
                                                   unsigned* __restrict__ bin_fill,
                                                   unsigned* __restrict__ binned, int E)
{
    __shared__ unsigned lh[NBMAX];
    __shared__ int goff[NBMAX];
    __shared__ unsigned sorted[CHUNK];
    int t = threadIdx.x;
    lh[t] = 0; lh[t + 256] = 0;
    __syncthreads();
    int e0 = blockIdx.x * CHUNK;

    unsigned pk[EPT]; int bn[EPT]; unsigned rk[EPT];
    #pragma unroll
    for (int i = 0; i < EPT; ++i) {
        int e = e0 + i * 256 + t;
        bn[i] = -1;
        if (e < E) {
            unsigned d = (unsigned)dst[e];
            pk[i] = (d << 16) | (unsigned)src[e];
            bn[i] = (int)(d >> 7);
            rk[i] = atomicAdd(&lh[bn[i]], 1u);
        }
    }
    __syncthreads();
    unsigned c0 = lh[t], c1 = lh[t + 256];   // own-bin counts (pre-scan)
    for (int off = 1; off < NBMAX; off <<= 1) {
        unsigned a = 0, b = 0;
        if (t >= off) a = lh[t - off];
        b = lh[t + 256 - off];
        __syncthreads();
        lh[t] += a; lh[t + 256] += b;
        __syncthreads();
    }
    unsigned x0 = lh[t] - c0, x1 = lh[t + 256] - c1;   // exclusive local bases
    if (c0) { unsigned g = atomicAdd(&bin_fill[t], c0);
              goff[t] = (int)(bin_base[t] + g) - (int)x0; }
    if (c1) { unsigned g = atomicAdd(&bin_fill[t + 256], c1);
              goff[t + 256] = (int)(bin_base[t + 256] + g) - (int)x1; }
    lh[t] = x0; lh[t + 256] = x1;            // own-entry overwrite only
    __syncthreads();
    #pragma unroll
    for (int i = 0; i < EPT; ++i)
        if (bn[i] >= 0) sorted[lh[bn[i]] + rk[i]] = pk[i];
    __syncthreads();
    int T = min(CHUNK, E - e0);
    for (int j = t; j < T; j += 256) {
        unsigned p = sorted[j];
        binned[goff[p >> 23] + j] = p;       // piecewise-contiguous runs
    }
}

// block per bin; LDS counting-sort by dst_local -> final dst-sorted csr_src + indptr
__global__ __launch_bounds__(256) void bin_finalize(const unsigned* __restrict__ binned,
                                                    const unsigned* __restrict__ bin_base,
                                                    int* __restrict__ csr_src,
                                                    int* __restrict__ indptr, int N)
{
    __shared__ unsigned lh[DB];
    __shared__ unsigned fill[DB];
    int t = threadIdx.x, b = blockIdx.x;
    unsigned base = bin_base[b];
    unsigned cnt = bin_base[b + 1] - base;
    if (t < DB) lh[t] = 0;
    __syncthreads();
    for (unsigned i = t; i < cnt; i += 256)
        atomicAdd(&lh[(binned[base + i] >> 16) & (DB - 1)], 1u);
    __syncthreads();
    unsigned c0 = (t < DB) ? lh[t] : 0;
    for (int off = 1; off < DB; off <<= 1) {
        unsigned a = 0;
        if (t >= off && t < DB) a = lh[t - off];
        __syncthreads();
        if (t < DB) lh[t] += a;
        __syncthreads();
    }
    if (t < DB) {
        unsigned excl = lh[t] - c0;
        int d = b * DB + t;
        if (d < N) indptr[d] = (int)(base + excl);
        fill[t] = excl;
    }
    __syncthreads();
    for (unsigned i = t; i < cnt; i += 256) {
        unsigned p = binned[base + i];
        unsigned pos = atomicAdd(&fill[(p >> 16) & (DB - 1)], 1u);
        csr_src[base + pos] = (int)(p & 0xFFFFu);
    }
}

// ==================== aggregation ====================
// Wave per node (1 node/wave, 12500 blocks). beg/end in SGPR -> csr_src reads are
// scalar loads; 16-deep independent VMEM gather chains (asrc dword + fp16 h row).
template <bool RELU>
__global__ __launch_bounds__(256) void aggregate(
    const __half* __restrict__ h, const float* __restrict__ asrc,
    const float* __restrict__ adst, const int* __restrict__ indptr,
    const int* __restrict__ csr_src, const float* __restrict__ bias,
    float* __restrict__ xout, int N, int nwaves)
{
    int lane = threadIdx.x & 63;
    int wid = blockIdx.x * 4 + __builtin_amdgcn_readfirstlane(threadIdx.x >> 6);
    unsigned h16 = (unsigned)(lane >> 4);   // head
    float bias_c = bias[lane];

    for (int node = wid; node < N; node += nwaves) {
        int beg = __builtin_amdgcn_readfirstlane(indptr[node]);
        int end = __builtin_amdgcn_readfirstlane(indptr[node + 1]);
        unsigned un = (unsigned)node;

        float adst_n = adst[un * 4u + h16];
        float p0 = __expf(lrelu(asrc[un * 4u + h16] + adst_n));   // self loop
        float sacc = p0;
        float acc = __half2float(h[un * 64u + (unsigned)lane]) * p0;

        int e = beg;
        for (; e + 16 <= end; e += 16) {
            int s[16]; float a[16], hv[16];
            #pragma unroll
            for (int i = 0; i < 16; ++i) s[i] = csr_src[e + i];          // scalar loads
            #pragma unroll
            for (int i = 0; i < 16; ++i) a[i] = asrc[(unsigned)s[i] * 4u + h16];
            #pragma unroll
            for (int i = 0; i < 16; ++i)
                hv[i] = __half2float(h[(unsigned)s[i] * 64u + (unsigned)lane]);
            #pragma unroll
            for (int i = 0; i < 16; ++i) {
                float p = __expf(lrelu(a[i] + adst_n));
                sacc += p;
                acc = fmaf(hv[i], p, acc);
            }
        }
        for (; e + 8 <= end; e += 8) {
            int s[8]; float a[8], hv[8];
            #pragma unroll
            for (int i = 0; i < 8; ++i) s[i] = csr_src[e + i];
            #pragma unroll
            for (int i = 0; i < 8; ++i) a[i] = asrc[(unsigned)s[i] * 4u + h16];
            #pragma unroll
            for (int i = 0; i < 8; ++i)
                hv[i] = __half2float(h[(unsigned)s[i] * 64u + (unsigned)lane]);
            #pragma unroll
            for (int i = 0; i < 8; ++i) {
                float p = __expf(lrelu(a[i] + adst_n));
                sacc += p;
                acc = fmaf(hv[i], p, acc);
            }
        }
        for (; e + 2 <= end; e += 2) {
            int s0 = csr_src[e], s1 = csr_src[e + 1];
            float a0 = asrc[(unsigned)s0 * 4u + h16];
            float a1 = asrc[(unsigned)s1 * 4u + h16];
            float h0 = __half2float(h[(unsigned)s0 * 64u + (unsigned)lane]);
            float h1 = __half2float(h[(unsigned)s1 * 64u + (unsigned)lane]);
            float pa = __expf(lrelu(a0 + adst_n));
            float pb = __expf(lrelu(a1 + adst_n));
            sacc += pa + pb;
            acc = fmaf(h0, pa, acc);
            acc = fmaf(h1, pb, acc);
        }
        if (e < end) {
            int s = csr_src[e];
            float p = __expf(lrelu(asrc[(unsigned)s * 4u + h16] + adst_n));
            sacc += p;
            acc = fmaf(__half2float(h[(unsigned)s * 64u + (unsigned)lane]), p, acc);
        }

        float o = acc / sacc + bias_c;
        if (RELU) o = fmaxf(o, 0.f);
        xout[un * 64u + (unsigned)lane] = o;
    }
}

// ---- fused scatter-mean pooling (batch_idx sorted -> binary search) + MLP head ----
__global__ void pool_mlp(const float* __restrict__ x, const int* __restrict__ batch, int N,
                         const float* __restrict__ W0, const float* __restrict__ b0,
                         const float* __restrict__ W1, const float* __restrict__ b1,
                         const float* __restrict__ W2, const float* __restrict__ b2,
                         const float* __restrict__ W3, const float* __restrict__ b3,
                         float* __restrict__ out)
{
    __shared__ int bounds[2];
    __shared__ float red[4][64];
    __shared__ float hb[64];
    int b = blockIdx.x, t = threadIdx.x;

    if (t < 2) {
        int target = b + t;
        int lo = 0, hi = N;
        while (lo < hi) {
            int mid = (lo + hi) >> 1;
            if (batch[mid] < target) lo = mid + 1; else hi = mid;
        }
        bounds[t] = lo;
    }
    __syncthreads();
    int beg = bounds[0], end = bounds[1];

    int c = t & 63, w = t >> 6;
    float sum = 0.f;
    for (int n = beg + w; n < end; n += 4) sum += x[(size_t)n * 64 + c];
    red[w][c] = sum;
    __syncthreads();
    if (t < 64) {
        float v = red[0][t] + red[1][t] + red[2][t] + red[3][t];
        float cb = fmaxf((float)(end - beg), 1.0f);
        hb[t] = v / cb;
    }
    __syncthreads();

    float v0 = 0.f;
    if (t < 64) {
        v0 = b0[t];
        for (int k = 0; k < 64; ++k) v0 = fmaf(hb[k], W0[k * 64 + t], v0);
        v0 = fmaxf(v0, 0.f);
    }
    __syncthreads(); if (t < 64) hb[t] = v0; __syncthreads();
    if (t < 64) {
        v0 = b1[t];
        for (int k = 0; k < 64; ++k) v0 = fmaf(hb[k], W1[k * 64 + t], v0);
        v0 = fmaxf(v0, 0.f);
    }
    __syncthreads(); if (t < 64) hb[t] = v0; __syncthreads();
    if (t < 64) {
        v0 = b2[t];
        for (int k = 0; k < 64; ++k) v0 = fmaf(hb[k], W2[k * 64 + t], v0);
        v0 = fmaxf(v0, 0.f);
    }
    __syncthreads(); if (t < 64) hb[t] = v0; __syncthreads();
    if (t < 64) {
        float r = hb[t] * W3[t];
        #pragma unroll
        for (int off = 32; off; off >>= 1) r += __shfl_xor(r, off);
        if (t == 0) out[b] = r + b3[0];
    }
}

extern "C" void kernel_launch(void* const* d_in, const int* in_sizes, int n_in,
                              void* d_out, int out_size, void* d_ws, size_t ws_size,
                              hipStream_t stream)
{
    const float* node_feats = (const float*)d_in[0];
    const float* glob       = (const float*)d_in[1];
    const int*   edge_index = (const int*)d_in[2];
    const int*   batch      = (const int*)d_in[3];
    const float* W[3]  = {(const float*)d_in[4],  (const float*)d_in[8],  (const float*)d_in[12]};
    const float* As[3] = {(const float*)d_in[5],  (const float*)d_in[9],  (const float*)d_in[13]};
    const float* Ad[3] = {(const float*)d_in[6],  (const float*)d_in[10], (const float*)d_in[14]};
    const float* Bi[3] = {(const float*)d_in[7],  (const float*)d_in[11], (const float*)d_in[15]};
    const float* mW0 = (const float*)d_in[16]; const float* mb0 = (const float*)d_in[17];
    const float* mW1 = (const float*)d_in[18]; const float* mb1 = (const float*)d_in[19];
    const float* mW2 = (const float*)d_in[20]; const float* mb2 = (const float*)d_in[21];
    const float* mW3 = (const float*)d_in[22]; const float* mb3 = (const float*)d_in[23];
    float* out = (float*)d_out;

    int N = in_sizes[0] / 9;
    int E = in_sizes[2] / 2;
    int B = in_sizes[1] / 4;
    const int* esrc = edge_index;
    const int* edst = edge_index + E;
    int nb = (N + DB - 1) / DB;

    // workspace layout
    char* ws = (char*)d_ws;
    size_t off = 0;
    auto alloc = [&](size_t bytes) -> void* {
        void* p = ws + off;
        off = (off + bytes + 255) & ~(size_t)255;
        return p;
    };
    __half*   hbuf     = (__half*)alloc((size_t)N * 64 * 2);
    float*    xbuf     = (float*)alloc((size_t)N * 64 * 4);
    float*    asrc     = (float*)alloc((size_t)N * GAT_H * 4);
    float*    adst     = (float*)alloc((size_t)N * GAT_H * 4);
    int*      indptr   = (int*)alloc((size_t)(N + 1) * 4);
    int*      csr_src  = (int*)alloc((size_t)E * 4);
    unsigned* binned   = (unsigned*)alloc((size_t)E * 4);
    unsigned* bin_cnt  = (unsigned*)alloc(NBMAX * 4);
    unsigned* bin_base = (unsigned*)alloc((NBMAX + 1) * 4);
    unsigned* bin_fill = (unsigned*)alloc(NBMAX * 4);
    (void)ws_size;

    // CSR build (binned counting sort; once — shared by all 3 layers)
    zero_small<<<1, 256, 0, stream>>>(bin_cnt, bin_fill);
    hist_bins<<<400, 256, 0, stream>>>(edst, bin_cnt, E);
    scan_bins<<<1, 256, 0, stream>>>(bin_cnt, bin_base, indptr, nb, N, E);
    bin_scatter<<<(E + CHUNK - 1) / CHUNK, 256, 0, stream>>>(esrc, edst, bin_base, bin_fill,
                                                             binned, E);
    bin_finalize<<<nb, 256, 0, stream>>>(binned, bin_base, csr_src, indptr, N);

    const int gemmBlocks = 1024;
    const int aggBlocks = 12500;    // 50000 waves -> 1 node per wave
    // layer 0 (K=13, concat fused)
    gemm_attn<13, true><<<gemmBlocks, 256, 0, stream>>>(nullptr, node_feats, glob, batch,
                                                        W[0], As[0], Ad[0], hbuf, asrc, adst,
                                                        N, gemmBlocks * 4);
    aggregate<true><<<aggBlocks, 256, 0, stream>>>(hbuf, asrc, adst, indptr, csr_src, Bi[0],
                                                   xbuf, N, aggBlocks * 4);
    // layer 1 (K=64)
    gemm_attn<64, false><<<gemmBlocks, 256, 0, stream>>>(xbuf, nullptr, nullptr, nullptr,
                                                         W[1], As[1], Ad[1], hbuf, asrc, adst,
                                                         N, gemmBlocks * 4);
    aggregate<true><<<aggBlocks, 256, 0, stream>>>(hbuf, asrc, adst, indptr, csr_src, Bi[1],
                                                   xbuf, N, aggBlocks * 4);
    // layer 2 (K=64, no act)
    gemm_attn<64, false><<<gemmBlocks, 256, 0, stream>>>(xbuf, nullptr, nullptr, nullptr,
                                                         W[2], As[2], Ad[2], hbuf, asrc, adst,
                                                         N, gemmBlocks * 4);
    aggregate<false><<<aggBlocks, 256, 0, stream>>>(hbuf, asrc, adst, indptr, csr_src, Bi[2],
                                                    xbuf, N, aggBlocks * 4);

    // fused pooling + MLP head
    pool_mlp<<<B, 256, 0, stream>>>(xbuf, batch, N,
                                    mW0, mb0, mW1, mb1, mW2, mb2, mW3, mb3, out);
}